// Round 15
// baseline (102.892 us; speedup 1.0000x reference)
//
#include <hip/hip_runtime.h>
#include <hip/hip_bf16.h>

namespace {

constexpr int kB = 4, kF = 64, kN = 4096;
constexpr int kM = kB * kF * kN;  // 1048576 total elements for std()

typedef __attribute__((ext_vector_type(8))) short bf16x8;
typedef __attribute__((ext_vector_type(4))) float f32x4;

__device__ __forceinline__ void wave_red2(float& s, float& q) {
#pragma unroll
  for (int o = 32; o > 0; o >>= 1) {
    s += __shfl_down(s, o, 64);
    q += __shfl_down(q, o, 64);
  }
}

// K1: 1024 blocks x 256 threads, each thread reduces 4 floats (float4 load).
__global__ void k_reduce1(const float* __restrict__ emb, float* __restrict__ part) {
  int t = blockIdx.x * blockDim.x + threadIdx.x;
  float4 v = reinterpret_cast<const float4*>(emb)[t];
  float s = v.x + v.y + v.z + v.w;
  float q = v.x * v.x + v.y * v.y + v.z * v.z + v.w * v.w;
  wave_red2(s, q);
  __shared__ float ls[4], lq[4];
  int lane = threadIdx.x & 63, w = threadIdx.x >> 6;
  if (lane == 0) { ls[w] = s; lq[w] = q; }
  __syncthreads();
  if (threadIdx.x == 0) {
    s = ls[0] + ls[1] + ls[2] + ls[3];
    q = lq[0] + lq[1] + lq[2] + lq[3];
    part[blockIdx.x] = s;
    part[1024 + blockIdx.x] = q;
  }
}

// K2: 256 blocks x 256 threads. Each block folds the 2048 partials itself
// (8 KB, L2-hit) -> inv_std, then converts 64 n-values: thread = (fq, nl).
// coordT[b][n][f] = bf16(emb[b][f][n] * inv_std); sq[b][n] = sum_f coord^2
// (sq from ROUNDED bf16 values so the diagonal of d2 is exactly 0).
__global__ __launch_bounds__(256) void k_convert(const float* __restrict__ emb,
                                                 const float* __restrict__ part,
                                                 unsigned short* __restrict__ coordT,
                                                 float* __restrict__ sq) {
  int t = threadIdx.x;
  float s = part[t] + part[t + 256] + part[t + 512] + part[t + 768];
  float q = part[1024 + t] + part[1280 + t] + part[1536 + t] + part[1792 + t];
  wave_red2(s, q);
  __shared__ float ls[4], lq[4];
  __shared__ float s_inv;
  int lane = t & 63, w = t >> 6;
  if (lane == 0) { ls[w] = s; lq[w] = q; }
  __syncthreads();
  if (t == 0) {
    s = ls[0] + ls[1] + ls[2] + ls[3];
    q = lq[0] + lq[1] + lq[2] + lq[3];
    float mean = s / (float)kM;
    float var = (q - s * mean) / (float)(kM - 1);  // Bessel ddof=1
    s_inv = 1.0f / sqrtf(var);
  }
  __syncthreads();
  float inv_std = s_inv;

  int nl = t & 63, fq = t >> 6;           // wave w == fq -> coalesced 256B loads
  int g = blockIdx.x * 64 + nl;           // [0, B*N)
  int b = g >> 12, n = g & 4095;
  const float* src = emb + ((size_t)b * kF + fq * 16) * kN + n;
  alignas(16) unsigned short loc[16];
  float acc = 0.f;
#pragma unroll
  for (int f = 0; f < 16; f++) {
    float v = src[(size_t)f * kN] * inv_std;
    union { __hip_bfloat16 h; unsigned short u; } cv;
    cv.h = __float2bfloat16(v);
    loc[f] = cv.u;
    float vf = __bfloat162float(cv.h);
    acc += vf * vf;
  }
  bf16x8* dst = reinterpret_cast<bf16x8*>(coordT + (size_t)g * kF + fq * 16);
  dst[0] = reinterpret_cast<const bf16x8*>(loc)[0];
  dst[1] = reinterpret_cast<const bf16x8*>(loc)[1];

  __shared__ float pacc[4][64];
  pacc[fq][nl] = acc;
  __syncthreads();
  if (fq == 0) sq[g] = pacc[0][nl] + pacc[1][nl] + pacc[2][nl] + pacc[3][nl];
}

// K3: out[y][x] = exp(-max(sq_x + sq_y - 2<c_x,c_y>, 0)/128)  (symmetric d2:
// value (x,y) written at (y,x) matches the reference).
// R15 CHANGE: block tile reshaped 64y x 256x -> 16y x 1024x. Store phase now
// writes 4 KB CONTIGUOUS per row touch (4 sequential 1KB wave-stores) vs
// 1 KB before. Theory: writes were DRAM-page-utilization-bound — 1 KB pieces
// at 16 KB stride use ~half of each ~2KB page; the 6.8 TB/s fills stream
// multi-KB per region. Retro-dicts R7 (512B pieces, worse) and why all
// instruction-level store changes (R6/R9/R11) were neutral.
// Wave = 16y x 256x: acc 16 x f32x4, af loaded per-m (low VGPR). LDS-staged,
// occ 2, band-order grid (R10), no XCD swizzle (R14 hurt), cached stores.
__global__ __launch_bounds__(256, 2) void k_gemm_exp(const unsigned short* __restrict__ coordT,
                                                     const float* __restrict__ sq,
                                                     float* __restrict__ out) {
  constexpr int kPitch = 1028;         // floats per LDS row (1024 + 4 pad)
  __shared__ float lds[16 * kPitch];   // 65.8 KB -> 2 blocks/CU

  int b = blockIdx.z;
  int wid = threadIdx.x >> 6;
  int lane = threadIdx.x & 63;
  int lhi = lane >> 4, llo = lane & 15;
  int y0 = blockIdx.y * 16;          // output rows (j side): 16 per block
  int x0 = blockIdx.x * 1024;        // output cols (i side) — FASTEST (bands)
  int xw = x0 + wid * 256;           // this wave's x-range (256 cols)
  const unsigned short* base = coordT + (size_t)b * kN * kF;
  const float* sqb = sq + (size_t)b * kN;

  // B fragment: the 16 y-rows (shared across the wave's 16 x-tiles)
  bf16x8 bf0, bf1;
  {
    const unsigned short* p = base + (size_t)(y0 + llo) * kF + lhi * 8;
    bf0 = *reinterpret_cast<const bf16x8*>(p);
    bf1 = *reinterpret_cast<const bf16x8*>(p + 32);
  }
  float sj = sqb[y0 + llo];

  // 16 x-tiles: load A fragments per-m inside the loop (keeps VGPR low),
  // 2 MFMAs per tile (K=64 in two k-steps).
  f32x4 acc[16];
#pragma unroll
  for (int m = 0; m < 16; m++) {
    const unsigned short* p = base + (size_t)(xw + m * 16 + llo) * kF + lhi * 8;
    bf16x8 a0 = *reinterpret_cast<const bf16x8*>(p);
    bf16x8 a1 = *reinterpret_cast<const bf16x8*>(p + 32);
    f32x4 z = {};
    z = __builtin_amdgcn_mfma_f32_16x16x32_bf16(a0, bf0, z, 0, 0, 0);
    acc[m] = __builtin_amdgcn_mfma_f32_16x16x32_bf16(a1, bf1, z, 0, 0, 0);
  }

  // epilogue -> LDS; acc tile m: x = xw + m*16 + lhi*4 + r, y = y0 + llo
  // exp(-max(raw,0)/64/2) = exp2(-max(raw,0) * log2(e)/128)
  constexpr float kC = -0.011271055f;  // 1.4426950408889634 / 128
#pragma unroll
  for (int m = 0; m < 16; m++) {
    f32x4 tv = *reinterpret_cast<const f32x4*>(&sqb[xw + m * 16 + lhi * 4]);
    f32x4 wv;
#pragma unroll
    for (int r = 0; r < 4; r++) {
      float raw = tv[r] + sj - 2.0f * acc[m][r];
      raw = fmaxf(raw, 0.0f);
      wv[r] = __builtin_amdgcn_exp2f(raw * kC);
    }
    int xloc = wid * 256 + m * 16 + lhi * 4;
    *reinterpret_cast<f32x4*>(&lds[llo * kPitch + xloc]) = wv;
  }
  __syncthreads();

  // Store phase: wave w owns rows [w*4, w*4+4); per row, 4 SEQUENTIAL
  // 1KB wave-stores = 4 KB contiguous per row touch.
  float* ob = out + (size_t)b * kN * kN + (size_t)y0 * kN + x0;
#pragma unroll
  for (int p = 0; p < 4; p++) {
    int yloc = wid * 4 + p;
    float* rp = ob + (size_t)yloc * kN;
#pragma unroll
    for (int c = 0; c < 4; c++) {
      f32x4 v = *reinterpret_cast<const f32x4*>(&lds[yloc * kPitch + c * 256 + lane * 4]);
      *reinterpret_cast<f32x4*>(rp + c * 256 + lane * 4) = v;
    }
  }
}

}  // namespace

extern "C" void kernel_launch(void* const* d_in, const int* in_sizes, int n_in,
                              void* d_out, int out_size, void* d_ws, size_t ws_size,
                              hipStream_t stream) {
  const float* emb = (const float*)d_in[1];  // d_in[0] = adj_in (unused by reference)
  float* out = (float*)d_out;

  // ws layout: [0, 16KB) reduction partials; coordT @16KB (2 MB); sq after.
  float* part = (float*)d_ws;
  unsigned short* coordT = (unsigned short*)((char*)d_ws + 16384);
  float* sq = (float*)((char*)d_ws + 16384 + (size_t)kB * kN * kF * sizeof(unsigned short));

  k_reduce1<<<1024, 256, 0, stream>>>(emb, part);
  k_convert<<<(kB * kN) / 64, 256, 0, stream>>>(emb, part, coordT, sq);
  dim3 grid(kN / 1024, kN / 16, kB);  // x (columns) fastest -> contiguous bands
  k_gemm_exp<<<grid, 256, 0, stream>>>(coordT, sq, out);
}

// Round 16
// 70.276 us; speedup vs baseline: 1.4641x; 1.4641x over previous
//
#include <hip/hip_runtime.h>
#include <hip/hip_bf16.h>

namespace {

constexpr int kB = 4, kF = 64, kN = 4096;
constexpr int kM = kB * kF * kN;  // 1048576 total elements for std()

typedef __attribute__((ext_vector_type(8))) short bf16x8;
typedef __attribute__((ext_vector_type(4))) float f32x4;

__device__ __forceinline__ void wave_red2(float& s, float& q) {
#pragma unroll
  for (int o = 32; o > 0; o >>= 1) {
    s += __shfl_down(s, o, 64);
    q += __shfl_down(q, o, 64);
  }
}

// K1: 512 blocks x 256 threads, each thread reduces 8 floats (2x float4).
__global__ void k_reduce1(const float* __restrict__ emb, float* __restrict__ part) {
  int t = blockIdx.x * blockDim.x + threadIdx.x;
  float4 v0 = reinterpret_cast<const float4*>(emb)[t * 2];
  float4 v1 = reinterpret_cast<const float4*>(emb)[t * 2 + 1];
  float s = (v0.x + v0.y) + (v0.z + v0.w) + (v1.x + v1.y) + (v1.z + v1.w);
  float q = v0.x * v0.x + v0.y * v0.y + v0.z * v0.z + v0.w * v0.w +
            v1.x * v1.x + v1.y * v1.y + v1.z * v1.z + v1.w * v1.w;
  wave_red2(s, q);
  __shared__ float ls[4], lq[4];
  int lane = threadIdx.x & 63, w = threadIdx.x >> 6;
  if (lane == 0) { ls[w] = s; lq[w] = q; }
  __syncthreads();
  if (threadIdx.x == 0) {
    s = ls[0] + ls[1] + ls[2] + ls[3];
    q = lq[0] + lq[1] + lq[2] + lq[3];
    part[blockIdx.x] = s;
    part[1024 + blockIdx.x] = q;
  }
}

// K2: 256 blocks x 256 threads. Each block folds the 512 partials itself
// (L2-hit) -> inv_std, then converts 64 n-values: thread = (fq, nl).
// coordT[b][n][f] = bf16(emb[b][f][n] * inv_std); sq[b][n] = sum_f coord^2
// (sq from ROUNDED bf16 values so the diagonal of d2 is exactly 0).
__global__ __launch_bounds__(256) void k_convert(const float* __restrict__ emb,
                                                 const float* __restrict__ part,
                                                 unsigned short* __restrict__ coordT,
                                                 float* __restrict__ sq) {
  int t = threadIdx.x;
  float s = part[t] + part[t + 256];
  float q = part[1024 + t] + part[1280 + t];
  wave_red2(s, q);
  __shared__ float ls[4], lq[4];
  __shared__ float s_inv;
  int lane = t & 63, w = t >> 6;
  if (lane == 0) { ls[w] = s; lq[w] = q; }
  __syncthreads();
  if (t == 0) {
    s = ls[0] + ls[1] + ls[2] + ls[3];
    q = lq[0] + lq[1] + lq[2] + lq[3];
    float mean = s / (float)kM;
    float var = (q - s * mean) / (float)(kM - 1);  // Bessel ddof=1
    s_inv = 1.0f / sqrtf(var);
  }
  __syncthreads();
  float inv_std = s_inv;

  int nl = t & 63, fq = t >> 6;           // wave w == fq -> coalesced 256B loads
  int g = blockIdx.x * 64 + nl;           // [0, B*N)
  int b = g >> 12, n = g & 4095;
  const float* src = emb + ((size_t)b * kF + fq * 16) * kN + n;
  alignas(16) unsigned short loc[16];
  float acc = 0.f;
#pragma unroll
  for (int f = 0; f < 16; f++) {
    float v = src[(size_t)f * kN] * inv_std;
    union { __hip_bfloat16 h; unsigned short u; } cv;
    cv.h = __float2bfloat16(v);
    loc[f] = cv.u;
    float vf = __bfloat162float(cv.h);
    acc += vf * vf;
  }
  bf16x8* dst = reinterpret_cast<bf16x8*>(coordT + (size_t)g * kF + fq * 16);
  dst[0] = reinterpret_cast<const bf16x8*>(loc)[0];
  dst[1] = reinterpret_cast<const bf16x8*>(loc)[1];

  __shared__ float pacc[4][64];
  pacc[fq][nl] = acc;
  __syncthreads();
  if (fq == 0) sq[g] = pacc[0][nl] + pacc[1][nl] + pacc[2][nl] + pacc[3][nl];
}

// K3 (R10 optimum, byte-identical): out[y][x] = exp(-max(sq_x+sq_y-2<cx,cy>,0)/128)
// (symmetric d2 -> value (x,y) at location (y,x) matches reference).
// 64y x 256x block tile; LDS-staged epilogue; 1KB-contiguous wave stores;
// band-ordered grid (blockIdx.x -> x0 fastest, +7us); occ 2 (3 hurts, twice);
// cached stores (NT neutral full-line, disastrous partial-line); no XCD
// swizzle (hurt). Mixed-stream BW here = 5.2 TB/s = 83% of measured copy
// ceiling — structural plateau for this op.
__global__ __launch_bounds__(256, 2) void k_gemm_exp(const unsigned short* __restrict__ coordT,
                                                     const float* __restrict__ sq,
                                                     float* __restrict__ out) {
  constexpr int kPitch = 260;  // floats per LDS row (256 + 4 pad)
  __shared__ float lds[64 * kPitch];  // 66.56 KB -> 2 blocks/CU

  int b = blockIdx.z;
  int wid = threadIdx.x >> 6;
  int lane = threadIdx.x & 63;
  int lhi = lane >> 4, llo = lane & 15;
  int y0 = blockIdx.y * 64;         // output rows (j side)
  int x0 = blockIdx.x * 256;        // output cols (i side) — FASTEST (bands)
  int xw = x0 + wid * 64;           // this wave's x-range
  const unsigned short* base = coordT + (size_t)b * kN * kF;

  // A fragments from x-rows, B fragments from y-rows (contig short8 per lane)
  bf16x8 af[4][2], bfr[4][2];
#pragma unroll
  for (int m = 0; m < 4; m++) {
    const unsigned short* p = base + (size_t)(xw + m * 16 + llo) * kF + lhi * 8;
    af[m][0] = *reinterpret_cast<const bf16x8*>(p);
    af[m][1] = *reinterpret_cast<const bf16x8*>(p + 32);
  }
#pragma unroll
  for (int n = 0; n < 4; n++) {
    const unsigned short* p = base + (size_t)(y0 + n * 16 + llo) * kF + lhi * 8;
    bfr[n][0] = *reinterpret_cast<const bf16x8*>(p);
    bfr[n][1] = *reinterpret_cast<const bf16x8*>(p + 32);
  }

  f32x4 acc[4][4] = {};
#pragma unroll
  for (int kk = 0; kk < 2; kk++)
#pragma unroll
    for (int m = 0; m < 4; m++)
#pragma unroll
      for (int n = 0; n < 4; n++)
        acc[m][n] = __builtin_amdgcn_mfma_f32_16x16x32_bf16(af[m][kk], bfr[n][kk], acc[m][n], 0, 0, 0);

  const float* sqb = sq + (size_t)b * kN;
  float si[4][4];
#pragma unroll
  for (int m = 0; m < 4; m++) {
    f32x4 tv = *reinterpret_cast<const f32x4*>(&sqb[xw + m * 16 + lhi * 4]);
    si[m][0] = tv[0]; si[m][1] = tv[1]; si[m][2] = tv[2]; si[m][3] = tv[3];
  }
  float sj[4];
#pragma unroll
  for (int n = 0; n < 4; n++) sj[n] = sqb[y0 + n * 16 + llo];

  // exp(-max(raw,0)/64/2) = exp2(-max(raw,0) * log2(e)/128)
  constexpr float kC = -0.011271055f;  // 1.4426950408889634 / 128
#pragma unroll
  for (int m = 0; m < 4; m++) {
#pragma unroll
    for (int n = 0; n < 4; n++) {
      f32x4 wv;
#pragma unroll
      for (int r = 0; r < 4; r++) {
        // acc layout: x = xw + m*16 + lhi*4 + r, y = y0 + n*16 + llo
        float raw = si[m][r] + sj[n] - 2.0f * acc[m][n][r];
        raw = fmaxf(raw, 0.0f);
        wv[r] = __builtin_amdgcn_exp2f(raw * kC);
      }
      int yloc = n * 16 + llo;
      int xloc = wid * 64 + m * 16 + lhi * 4;
      *reinterpret_cast<f32x4*>(&lds[yloc * kPitch + xloc]) = wv;
    }
  }
  __syncthreads();

  // Store phase: wave w streams rows [w*16, w*16+16); each row = one
  // 1KB-contiguous wave store (64 lanes x 16B), fully covering 8 x 128B lines.
  float* ob = out + (size_t)b * kN * kN + (size_t)y0 * kN + x0;
#pragma unroll
  for (int p = 0; p < 16; p++) {
    int yloc = wid * 16 + p;
    f32x4 v = *reinterpret_cast<const f32x4*>(&lds[yloc * kPitch + lane * 4]);
    *reinterpret_cast<f32x4*>(ob + (size_t)yloc * kN + lane * 4) = v;
  }
}

}  // namespace

extern "C" void kernel_launch(void* const* d_in, const int* in_sizes, int n_in,
                              void* d_out, int out_size, void* d_ws, size_t ws_size,
                              hipStream_t stream) {
  const float* emb = (const float*)d_in[1];  // d_in[0] = adj_in (unused by reference)
  float* out = (float*)d_out;

  // ws layout: [0, 16KB) reduction partials; coordT @16KB (2 MB); sq after.
  float* part = (float*)d_ws;
  unsigned short* coordT = (unsigned short*)((char*)d_ws + 16384);
  float* sq = (float*)((char*)d_ws + 16384 + (size_t)kB * kN * kF * sizeof(unsigned short));

  k_reduce1<<<512, 256, 0, stream>>>(emb, part);
  k_convert<<<(kB * kN) / 64, 256, 0, stream>>>(emb, part, coordT, sq);
  dim3 grid(kN / 256, kN / 64, kB);  // x (columns) fastest -> contiguous bands
  k_gemm_exp<<<grid, 256, 0, stream>>>(coordT, sq, out);
}